// Round 7
// baseline (203.486 us; speedup 1.0000x reference)
//
#include <hip/hip_runtime.h>
#include <stdint.h>

// ---------------------------------------------------------------------------
// Bit-exact replica of XLA:CPU's f32 exp (GenerateVF32Exp, Cephes/Eigen pexp)
// as compiled with TargetOptions.AllowFPOpFusion == Fast (x86 FMA fusion).
// gfx950 v_fma_f32 == x86 vfmadd (IEEE single rounding). VERIFIED bit-exact
// rounds 3-6 (absmax 0.0) — do not modify.
// ---------------------------------------------------------------------------
__device__ __forceinline__ float xla_cpu_expf_fused(float x) {
#pragma clang fp contract(off)
  const float exp_hi = 88.3762626647950f;
  const float exp_lo = -88.3762626647949f;
  const float log2ef = 1.44269504088896341f;
  const float c1 = 0.693359375f;
  const float c2 = -2.12194440e-4f;
  const float p0 = 1.9875691500e-4f;
  const float p1 = 1.3981999507e-3f;
  const float p2 = 8.3334519073e-3f;
  const float p3 = 4.1665795894e-2f;
  const float p4 = 1.6666665459e-1f;
  const float p5 = 5.0000001201e-1f;

  float xc = fminf(fmaxf(x, exp_lo), exp_hi);
  float fx = floorf(__builtin_fmaf(xc, log2ef, 0.5f));
  float xr = __builtin_fmaf(-c1, fx, xc);
  xr = __builtin_fmaf(-c2, fx, xr);

  float z2 = xr * xr;
  float y = __builtin_fmaf(xr, p0, p1);
  y = __builtin_fmaf(y, xr, p2);
  y = __builtin_fmaf(y, xr, p3);
  y = __builtin_fmaf(y, xr, p4);
  y = __builtin_fmaf(y, xr, p5);
  y = __builtin_fmaf(y, z2, xr);
  y = 1.0f + y;

  int n = (int)fx;
  float p2n = __int_as_float((n + 127) << 23);
  float res = y * p2n;
  return fmaxf(res, x);
}

__device__ __forceinline__ float silu_ref(float v) {
#pragma clang fp contract(off)
  float t = xla_cpu_expf_fused(-v);
  float s = 1.0f / (1.0f + t);   // IEEE correctly-rounded divide
  return v * s;
}

typedef uint32_t u32x4 __attribute__((ext_vector_type(4)));

// Per-uint4 pulse work: pack nibble -> 8-lane OR-butterfly -> silu -> unpack.
// Each aligned 8-lane group owns one value; silu computed redundantly x8
// (VALU ~8% of cycle budget -> free). sh = 28 - 4*(lane&7).
__device__ __forceinline__ u32x4 process4(u32x4 w, int sh) {
  uint32_t nib = ((w[0] != 0u) ? 8u : 0u) | ((w[1] != 0u) ? 4u : 0u) |
                 ((w[2] != 0u) ? 2u : 0u) | ((w[3] != 0u) ? 1u : 0u);
  uint32_t u = nib << sh;
  u |= (uint32_t)__shfl_xor((int)u, 1);
  u |= (uint32_t)__shfl_xor((int)u, 2);
  u |= (uint32_t)__shfl_xor((int)u, 4);

  const float v = __uint_as_float(u);
  const uint32_t ru = __float_as_uint(silu_ref(v));

  const uint32_t nib4 = (ru >> sh) & 0xFu;
  u32x4 o;
  o[0] = (nib4 & 8u) ? 0x3F800000u : 0u;
  o[1] = (nib4 & 4u) ? 0x3F800000u : 0u;
  o[2] = (nib4 & 2u) ? 0x3F800000u : 0u;
  o[3] = (nib4 & 1u) ? 0x3F800000u : 0u;
  return o;
}

// Coalesced + 8-deep MLP, occupancy-pinned:
//  - lane L loads uint4 (base + L): each wave covers 1 KB contiguous/instr.
//  - 8 loads per thread at offsets j*blockDim (block spans 32 KB contiguous)
//    issued back-to-back -> 8 outstanding VMEM ops/wave (consumer of w_k
//    waits at vmcnt(7-k)), then processed+stored sequentially so the live
//    set shrinks as loads retire (peak ~55 VGPR).
//  - __launch_bounds__(256, 8): pin 8 waves/SIMD -> allocator capped at
//    64 VGPR (round-5 lesson: unpinned interleave blew past 64 -> 251us).
__global__ __launch_bounds__(256, 8) void spike_silu_kernel(
    const u32x4* __restrict__ in, u32x4* __restrict__ out, int n4) {
  const int bdim = blockDim.x;                       // 256
  const int stride8 = gridDim.x * bdim * 8;
  const int sh = 28 - 4 * (threadIdx.x & 7);
  int i0 = blockIdx.x * bdim * 8 + threadIdx.x;

  for (; i0 + 7 * bdim < n4; i0 += stride8) {
    u32x4 w0 = in[i0];
    u32x4 w1 = in[i0 + bdim];
    u32x4 w2 = in[i0 + 2 * bdim];
    u32x4 w3 = in[i0 + 3 * bdim];
    u32x4 w4 = in[i0 + 4 * bdim];
    u32x4 w5 = in[i0 + 5 * bdim];
    u32x4 w6 = in[i0 + 6 * bdim];
    u32x4 w7 = in[i0 + 7 * bdim];

    out[i0] = process4(w0, sh);
    out[i0 + bdim] = process4(w1, sh);
    out[i0 + 2 * bdim] = process4(w2, sh);
    out[i0 + 3 * bdim] = process4(w3, sh);
    out[i0 + 4 * bdim] = process4(w4, sh);
    out[i0 + 5 * bdim] = process4(w5, sh);
    out[i0 + 6 * bdim] = process4(w6, sh);
    out[i0 + 7 * bdim] = process4(w7, sh);
  }
  // tail (does not execute for n4 = 2^25: 8 exact sweeps) — kept for safety
  for (; i0 < n4; i0 += bdim) {
    out[i0] = process4(in[i0], sh);
  }
}

extern "C" void kernel_launch(void* const* d_in, const int* in_sizes, int n_in,
                              void* d_out, int out_size, void* d_ws, size_t ws_size,
                              hipStream_t stream) {
  (void)in_sizes; (void)n_in; (void)d_ws; (void)ws_size;
  const u32x4* in = reinterpret_cast<const u32x4*>(d_in[0]);
  u32x4* out = reinterpret_cast<u32x4*>(d_out);
  const int n4 = out_size / 4;  // 33,554,432 uint4s (16 B each)

  const int threads = 256;
  const int blocks = 2048;  // 8 sweeps of blocks*threads*8 == n4 exactly
  spike_silu_kernel<<<blocks, threads, 0, stream>>>(in, out, n4);
}

// Round 8
// 200.067 us; speedup vs baseline: 1.0171x; 1.0171x over previous
//
#include <hip/hip_runtime.h>
#include <stdint.h>

// ---------------------------------------------------------------------------
// FINAL (round-6 best: 200.3 us, 5.36 TB/s logical = 85% of D2D-copy ceiling).
// Bit-exact replica of XLA:CPU's f32 exp (GenerateVF32Exp, Cephes/Eigen pexp)
// as compiled with TargetOptions.AllowFPOpFusion == Fast (x86 FMA fusion).
// gfx950 v_fma_f32 == x86 vfmadd (IEEE single rounding). VERIFIED bit-exact
// rounds 3-7 (absmax 0.0) — do not modify.
// ---------------------------------------------------------------------------
__device__ __forceinline__ float xla_cpu_expf_fused(float x) {
#pragma clang fp contract(off)
  const float exp_hi = 88.3762626647950f;
  const float exp_lo = -88.3762626647949f;
  const float log2ef = 1.44269504088896341f;
  const float c1 = 0.693359375f;
  const float c2 = -2.12194440e-4f;
  const float p0 = 1.9875691500e-4f;
  const float p1 = 1.3981999507e-3f;
  const float p2 = 8.3334519073e-3f;
  const float p3 = 4.1665795894e-2f;
  const float p4 = 1.6666665459e-1f;
  const float p5 = 5.0000001201e-1f;

  float xc = fminf(fmaxf(x, exp_lo), exp_hi);
  float fx = floorf(__builtin_fmaf(xc, log2ef, 0.5f));
  float xr = __builtin_fmaf(-c1, fx, xc);
  xr = __builtin_fmaf(-c2, fx, xr);

  float z2 = xr * xr;
  float y = __builtin_fmaf(xr, p0, p1);
  y = __builtin_fmaf(y, xr, p2);
  y = __builtin_fmaf(y, xr, p3);
  y = __builtin_fmaf(y, xr, p4);
  y = __builtin_fmaf(y, xr, p5);
  y = __builtin_fmaf(y, z2, xr);
  y = 1.0f + y;

  int n = (int)fx;
  float p2n = __int_as_float((n + 127) << 23);
  float res = y * p2n;
  return fmaxf(res, x);
}

__device__ __forceinline__ float silu_ref(float v) {
#pragma clang fp contract(off)
  float t = xla_cpu_expf_fused(-v);
  float s = 1.0f / (1.0f + t);   // IEEE correctly-rounded divide
  return v * s;
}

typedef uint32_t u32x4 __attribute__((ext_vector_type(4)));

// Per-uint4 pulse work: pack nibble -> 8-lane OR-butterfly -> silu -> unpack.
// Each aligned 8-lane group owns one value; silu computed redundantly x8
// (VALU ~8% of cycle budget -> free). sh = 28 - 4*(lane&7).
__device__ __forceinline__ u32x4 process4(u32x4 w, int sh) {
  uint32_t nib = ((w[0] != 0u) ? 8u : 0u) | ((w[1] != 0u) ? 4u : 0u) |
                 ((w[2] != 0u) ? 2u : 0u) | ((w[3] != 0u) ? 1u : 0u);
  uint32_t u = nib << sh;
  u |= (uint32_t)__shfl_xor((int)u, 1);
  u |= (uint32_t)__shfl_xor((int)u, 2);
  u |= (uint32_t)__shfl_xor((int)u, 4);

  const float v = __uint_as_float(u);
  const uint32_t ru = __float_as_uint(silu_ref(v));

  const uint32_t nib4 = (ru >> sh) & 0xFu;
  u32x4 o;
  o[0] = (nib4 & 8u) ? 0x3F800000u : 0u;
  o[1] = (nib4 & 4u) ? 0x3F800000u : 0u;
  o[2] = (nib4 & 2u) ? 0x3F800000u : 0u;
  o[3] = (nib4 & 1u) ? 0x3F800000u : 0u;
  return o;
}

// Coalesced + 4-deep MLP, occupancy-pinned (best measured configuration):
//  - lane L loads uint4 (base + L): each wave covers 1 KB contiguous/instr.
//  - 4 loads per thread at offsets j*blockDim (block spans 16 KB contiguous),
//    issued back-to-back -> 4 outstanding VMEM ops/wave, then processed+
//    stored sequentially to keep the live set small.
//  - __launch_bounds__(256, 8): pin 8 waves/SIMD, allocator capped <=64 VGPR
//    (round-5 lesson: unpinned interleave blew past 64 -> 251 us).
//  - 8-deep variant measured 203.5 us (neutral-negative): queue depth is not
//    the limiter at this point; DRAM read/write-mix turnaround is.
__global__ __launch_bounds__(256, 8) void spike_silu_kernel(
    const u32x4* __restrict__ in, u32x4* __restrict__ out, int n4) {
  const int bdim = blockDim.x;                      // 256
  const int stride4 = gridDim.x * bdim * 4;
  const int sh = 28 - 4 * (threadIdx.x & 7);
  int i0 = blockIdx.x * bdim * 4 + threadIdx.x;

  for (; i0 + 3 * bdim < n4; i0 += stride4) {
    u32x4 w0 = in[i0];
    u32x4 w1 = in[i0 + bdim];
    u32x4 w2 = in[i0 + 2 * bdim];
    u32x4 w3 = in[i0 + 3 * bdim];

    out[i0] = process4(w0, sh);
    out[i0 + bdim] = process4(w1, sh);
    out[i0 + 2 * bdim] = process4(w2, sh);
    out[i0 + 3 * bdim] = process4(w3, sh);
  }
  // tail (does not execute for n4 = 2^25: 16 exact sweeps) — kept for safety
  for (; i0 < n4; i0 += bdim) {
    out[i0] = process4(in[i0], sh);
  }
}

extern "C" void kernel_launch(void* const* d_in, const int* in_sizes, int n_in,
                              void* d_out, int out_size, void* d_ws, size_t ws_size,
                              hipStream_t stream) {
  (void)in_sizes; (void)n_in; (void)d_ws; (void)ws_size;
  const u32x4* in = reinterpret_cast<const u32x4*>(d_in[0]);
  u32x4* out = reinterpret_cast<u32x4*>(d_out);
  const int n4 = out_size / 4;  // 33,554,432 uint4s (16 B each)

  const int threads = 256;
  const int blocks = 2048;  // 16 sweeps of blocks*threads*4 == n4 exactly
  spike_silu_kernel<<<blocks, threads, 0, stream>>>(in, out, n4);
}